// Round 8
// baseline (561.358 us; speedup 1.0000x reference)
//
#include <hip/hip_runtime.h>

// Problem constants
#define NB      32      // batch
#define INF     128     // in_flt
#define NPIX    64      // N
#define TSP     16      // t
#define OUTF    32      // out_flt
#define FF      16      // intermediate features
#define D_IN    768     // 3*t*t
#define D_OUT   8192    // out_flt*t*t
#define NCOL    (D_OUT*FF)   // 131072
#define OUTCH   160     // in_flt + out_flt
#define BSTRIDE 655360  // 160*64*64 floats per batch in d_out
#define MOFF    524288  // 128*64*64: offset of out_a region per batch (M scratch)

// K1: fused strided conv (128ch,4x4,stride4 -> 3ch) + x->out concat copy.
__global__ __launch_bounds__(256) void k1_conv_copy(
    const float* __restrict__ x, const float* __restrict__ wc,
    float* __restrict__ out, float* __restrict__ At)
{
    __shared__ float sW[3*128*16];     // w_conv, 24 KB
    __shared__ float sP[16][16][3];    // partials [icg][j][c3]
    const int b   = blockIdx.x >> 4;
    const int oi  = blockIdx.x & 15;
    const int tid = threadIdx.x;
    for (int idx = tid; idx < 6144; idx += 256) sW[idx] = wc[idx];
    __syncthreads();
    const int icg = tid >> 4;          // 0..15 -> ic block of 8
    const int j   = tid & 15;          // output col
    float a0 = 0.f, a1 = 0.f, a2 = 0.f;
    for (int ic8 = 0; ic8 < 8; ++ic8) {
        const int ic = icg*8 + ic8;
        #pragma unroll
        for (int ki = 0; ki < 4; ++ki) {
            const int row = 4*oi + ki;
            const float4 xv = *(const float4*)(x + ((size_t)(b*INF+ic)*NPIX + row)*NPIX + 4*j);
            *(float4*)(out + ((size_t)(b*OUTCH+ic)*NPIX + row)*NPIX + 4*j) = xv;
            const float* w0 = sW + ((0*INF+ic)*4 + ki)*4;
            const float* w1 = sW + ((1*INF+ic)*4 + ki)*4;
            const float* w2 = sW + ((2*INF+ic)*4 + ki)*4;
            a0 += xv.x*w0[0] + xv.y*w0[1] + xv.z*w0[2] + xv.w*w0[3];
            a1 += xv.x*w1[0] + xv.y*w1[1] + xv.z*w1[2] + xv.w*w1[3];
            a2 += xv.x*w2[0] + xv.y*w2[1] + xv.z*w2[2] + xv.w*w2[3];
        }
    }
    sP[icg][j][0] = a0; sP[icg][j][1] = a1; sP[icg][j][2] = a2;
    __syncthreads();
    if (tid < 48) {
        const int c3 = tid >> 4, jj = tid & 15;
        float s = 0.f;
        #pragma unroll
        for (int g = 0; g < 16; ++g) s += sP[g][jj][c3];
        const int k = c3*256 + oi*16 + jj;    // reshape(3,16,16) C-order
        At[k*32 + b] = s;
    }
}

// K2 v8 == v7 wrapped in rep=0..3 (DIAGNOSIS: amplify k2 4x so it tops the
// rocprof list and exposes its hbm_gbps/FETCH/VALUBusy/LDS_CONFLICT; body
// idempotent -> result unchanged. R0-R7 never saw k2's counters; fills
// (~230us) hide everything below 226us.)
__global__ __launch_bounds__(512, 2) void k2_gemm(
    const float* __restrict__ At, const float* __restrict__ Tm,
    float* __restrict__ out)
{
    extern __shared__ float sA[];      // (D_IN+1)*32 floats = 96 KB + 128 B
    const int tid = threadIdx.x;
    {   // stage all of At, coalesced float4
        const float4* src = (const float4*)At;
        float4* dst = (float4*)sA;
        #pragma unroll
        for (int i = 0; i < 12; ++i)
            dst[tid + i*512] = src[tid + i*512];
    }
    __syncthreads();
    const int w    = tid >> 6;                 // wave 0..7
    const int lane = tid & 63;
    const int bg   = w >> 1;                   // batch-group of 8 (wave-uniform)
    const int col4 = blockIdx.x*512 + (w & 1)*256 + lane*4;  // unique per lane

    const float* tp    = Tm + col4;
    const float* aBase = sA + bg*8;            // wave-uniform -> ds broadcast

    for (int rep = 0; rep < 4; ++rep) {
        float acc[8][4];
        #pragma unroll
        for (int i = 0; i < 8; ++i)
            #pragma unroll
            for (int j = 0; j < 4; ++j) acc[i][j] = 0.f;

#define TLD(KK) (*(const float4*)(tp + (size_t)(KK)*NCOL))
#define FM32(T4, AL, AH) { \
  acc[0][0]+=AL.x*T4.x; acc[0][1]+=AL.x*T4.y; acc[0][2]+=AL.x*T4.z; acc[0][3]+=AL.x*T4.w; \
  acc[1][0]+=AL.y*T4.x; acc[1][1]+=AL.y*T4.y; acc[1][2]+=AL.y*T4.z; acc[1][3]+=AL.y*T4.w; \
  acc[2][0]+=AL.z*T4.x; acc[2][1]+=AL.z*T4.y; acc[2][2]+=AL.z*T4.z; acc[2][3]+=AL.z*T4.w; \
  acc[3][0]+=AL.w*T4.x; acc[3][1]+=AL.w*T4.y; acc[3][2]+=AL.w*T4.z; acc[3][3]+=AL.w*T4.w; \
  acc[4][0]+=AH.x*T4.x; acc[4][1]+=AH.x*T4.y; acc[4][2]+=AH.x*T4.z; acc[4][3]+=AH.x*T4.w; \
  acc[5][0]+=AH.y*T4.x; acc[5][1]+=AH.y*T4.y; acc[5][2]+=AH.y*T4.z; acc[5][3]+=AH.y*T4.w; \
  acc[6][0]+=AH.z*T4.x; acc[6][1]+=AH.z*T4.y; acc[6][2]+=AH.z*T4.z; acc[6][3]+=AH.z*T4.w; \
  acc[7][0]+=AH.w*T4.x; acc[7][1]+=AH.w*T4.y; acc[7][2]+=AH.w*T4.z; acc[7][3]+=AH.w*T4.w; }
#define STEP(J, TT) { \
    const float4 naL = *(const float4*)(aBase + (k0+(J)+1)*32); \
    const float4 naH = *(const float4*)(aBase + (k0+(J)+1)*32 + 4); \
    FM32(TT, aL, aH); TT = TLD(k0 + 8 + (J)); \
    aL = naL; aH = naH; }
#define STEPE(J, TT) { \
    const float4 naL = *(const float4*)(aBase + (k0+(J)+1)*32); \
    const float4 naH = *(const float4*)(aBase + (k0+(J)+1)*32 + 4); \
    FM32(TT, aL, aH); \
    aL = naL; aH = naH; }

        float4 t0=TLD(0), t1=TLD(1), t2=TLD(2), t3=TLD(3),
               t4=TLD(4), t5=TLD(5), t6=TLD(6), t7=TLD(7);
        float4 aL = *(const float4*)(aBase);       // k=0 row
        float4 aH = *(const float4*)(aBase + 4);

        int k0 = 0;
        for (; k0 < D_IN - 8; k0 += 8) {
            STEP(0, t0) STEP(1, t1) STEP(2, t2) STEP(3, t3)
            STEP(4, t4) STEP(5, t5) STEP(6, t6) STEP(7, t7)
        }
        // epilogue: k0 == D_IN-8, consume only (last prefetch hits the pad row)
        STEPE(0, t0) STEPE(1, t1) STEPE(2, t2) STEPE(3, t3)
        STEPE(4, t4) STEPE(5, t5) STEPE(6, t6) STEPE(7, t7)
#undef STEPE
#undef STEP
#undef FM32
#undef TLD

        #pragma unroll
        for (int bb = 0; bb < 8; ++bb)
            *(float4*)(out + (size_t)(bg*8 + bb)*BSTRIDE + MOFF + col4) =
                make_float4(acc[bb][0], acc[bb][1], acc[bb][2], acc[bb][3]);
    }
}

// K3: out[j,d] = sum_i exp(-sum_f |M[i,d,f]-M[j,d,f]|) - 1.
__global__ __launch_bounds__(256) void k3_pairs(
    const float* __restrict__ outM,    // d_out base (M lives in out_a slots)
    float* __restrict__ outS)
{
    extern __shared__ float sM[];      // 32*32*17 floats
    const int tid = threadIdx.x;
    const int dd0 = blockIdx.x * 32;
    for (int idx = tid; idx < 32*32*16; idx += 256) {
        const int i = idx >> 9, rem = idx & 511, d = rem >> 4, f = rem & 15;
        sM[(i*32 + d)*17 + f] =
            outM[(size_t)i*BSTRIDE + MOFF + (size_t)(dd0 + d)*16 + f];
    }
    __syncthreads();
    const int j = tid >> 3;
    for (int q = 0; q < 4; ++q) {
        const int d = (tid & 7) + q*8;
        float mj[16];
        const float* pj = sM + (j*32 + d)*17;
        #pragma unroll
        for (int f = 0; f < 16; ++f) mj[f] = pj[f];
        float acc = 0.f;
        for (int i = 0; i < 32; ++i) {
            const float* pi = sM + (i*32 + d)*17;
            float dist = 0.f;
            #pragma unroll
            for (int f = 0; f < 16; ++f) dist += fabsf(pi[f] - mj[f]);
            acc += __expf(-dist);
        }
        outS[(size_t)j*D_OUT + dd0 + d] = acc - 1.0f;
    }
}

// K4: ConvTranspose2d, stride==kernel -> no overlap.
__global__ __launch_bounds__(256) void k4_deconv(
    const float* __restrict__ outS, const float* __restrict__ wd,
    float* __restrict__ out)
{
    __shared__ float sO[32*256];       // [ic][si*16+sj]
    __shared__ float sWd[32*16];       // [ic][ki*4+kj]
    const int b   = blockIdx.x >> 5;
    const int oc  = blockIdx.x & 31;
    const int tid = threadIdx.x;
    for (int idx = tid; idx < 8192; idx += 256) sO[idx] = outS[(size_t)b*D_OUT + idx];
    for (int idx = tid; idx < 512; idx += 256) {
        const int ic = idx >> 4, r = idx & 15;
        sWd[idx] = wd[((ic*32 + oc) << 4) + r];   // IOHW: (ic, oc, ki, kj)
    }
    __syncthreads();
    float* ob = out + (size_t)b*BSTRIDE + (size_t)(128 + oc)*4096;
    for (int s = 0; s < 16; ++s) {
        const int p  = tid + (s << 8);
        const int i  = p >> 6, jc = p & 63;
        const int si = i >> 2, ki = i & 3, sj = jc >> 2, kj = jc & 3;
        float acc = 0.f;
        #pragma unroll
        for (int ic = 0; ic < 32; ++ic)
            acc += sO[ic*256 + si*16 + sj] * sWd[ic*16 + ki*4 + kj];
        ob[p] = acc;
    }
}

extern "C" void kernel_launch(void* const* d_in, const int* in_sizes, int n_in,
                              void* d_out, int out_size, void* d_ws, size_t ws_size,
                              hipStream_t stream) {
    const float* x  = (const float*)d_in[0];
    const float* wc = (const float*)d_in[1];
    const float* Tm = (const float*)d_in[2];
    const float* wd = (const float*)d_in[3];
    float* out  = (float*)d_out;
    float* At   = (float*)d_ws;                        // 98304 B
    float* outS = (float*)((char*)d_ws + (1 << 17));   // 1 MB at +128 KB

    k1_conv_copy<<<NB*TSP, 256, 0, stream>>>(x, wc, out, At);                   // 512 blocks
    k2_gemm    <<<NCOL/512, 512, (D_IN+1)*32*sizeof(float), stream>>>(At, Tm, out); // 256 blocks
    k3_pairs   <<<D_OUT/32, 256, 32*32*17*sizeof(float), stream>>>(out, outS);  // 256 blocks
    k4_deconv  <<<NB*OUTF, 256, 0, stream>>>(outS, wd, out);                    // 1024 blocks
}

// Round 9
// 221.687 us; speedup vs baseline: 2.5322x; 2.5322x over previous
//
#include <hip/hip_runtime.h>

// Problem constants
#define NB      32      // batch
#define INF     128     // in_flt
#define NPIX    64      // N
#define TSP     16      // t
#define OUTF    32      // out_flt
#define FF      16      // intermediate features
#define D_IN    768     // 3*t*t
#define KHALF   384     // D_IN/2 (split-k)
#define D_OUT   8192    // out_flt*t*t
#define NCOL    (D_OUT*FF)   // 131072
#define OUTCH   160     // in_flt + out_flt
#define BSTRIDE 655360  // 160*64*64 floats per batch in d_out

// K1: fused strided conv (128ch,4x4,stride4 -> 3ch) + x->out concat copy.
// A written k-major: At[k*32 + b].
__global__ __launch_bounds__(256) void k1_conv_copy(
    const float* __restrict__ x, const float* __restrict__ wc,
    float* __restrict__ out, float* __restrict__ At)
{
    __shared__ float sW[3*128*16];     // w_conv, 24 KB
    __shared__ float sP[16][16][3];    // partials [icg][j][c3]
    const int b   = blockIdx.x >> 4;
    const int oi  = blockIdx.x & 15;
    const int tid = threadIdx.x;
    for (int idx = tid; idx < 6144; idx += 256) sW[idx] = wc[idx];
    __syncthreads();
    const int icg = tid >> 4;          // 0..15 -> ic block of 8
    const int j   = tid & 15;          // output col
    float a0 = 0.f, a1 = 0.f, a2 = 0.f;
    for (int ic8 = 0; ic8 < 8; ++ic8) {
        const int ic = icg*8 + ic8;
        #pragma unroll
        for (int ki = 0; ki < 4; ++ki) {
            const int row = 4*oi + ki;
            const float4 xv = *(const float4*)(x + ((size_t)(b*INF+ic)*NPIX + row)*NPIX + 4*j);
            *(float4*)(out + ((size_t)(b*OUTCH+ic)*NPIX + row)*NPIX + 4*j) = xv;
            const float* w0 = sW + ((0*INF+ic)*4 + ki)*4;
            const float* w1 = sW + ((1*INF+ic)*4 + ki)*4;
            const float* w2 = sW + ((2*INF+ic)*4 + ki)*4;
            a0 += xv.x*w0[0] + xv.y*w0[1] + xv.z*w0[2] + xv.w*w0[3];
            a1 += xv.x*w1[0] + xv.y*w1[1] + xv.z*w1[2] + xv.w*w1[3];
            a2 += xv.x*w2[0] + xv.y*w2[1] + xv.z*w2[2] + xv.w*w2[3];
        }
    }
    sP[icg][j][0] = a0; sP[icg][j][1] = a1; sP[icg][j][2] = a2;
    __syncthreads();
    if (tid < 48) {
        const int c3 = tid >> 4, jj = tid & 15;
        float s = 0.f;
        #pragma unroll
        for (int g = 0; g < 16; ++g) s += sP[g][jj][c3];
        const int k = c3*256 + oi*16 + jj;    // reshape(3,16,16) C-order
        At[k*32 + b] = s;
    }
}

// K2 v9: SPLIT-K(2). R8 counters (k2x4): hbm 24% peak, VALUBusy 46.5%,
// Occupancy 22.8% (8 waves/CU; 96KB LDS -> 1 block/CU), and rep-time
// INVARIANT to 60% L3 hits -> latency-throughput-bound, not bytes-bound.
// Fix: halve the k-range per block -> sA = 48 KB, VGPR<=128 -> 2 blocks/CU
// = 16 waves/CU (4 waves/SIMD): 2x issue parallelism + 2x in-flight loads.
// Partials Mp[h][b][col] go to ws; K3 sums the two halves on load.
// Keeps: unique-col waves, 8-deep named-reg T-ring on a pure vmcnt queue.
__global__ __launch_bounds__(512, 4) void k2_gemm(
    const float* __restrict__ At, const float* __restrict__ Tm,
    float* __restrict__ Mp)
{
    extern __shared__ float sA[];      // KHALF*32 floats = 48 KB
    const int tid  = threadIdx.x;
    const int half = blockIdx.x >> 8;  // 0..1 k-half
    const int cblk = blockIdx.x & 255; // 256 col-blocks
    {   // stage this half's A slice, coalesced float4
        const float4* src = (const float4*)(At + (size_t)half*KHALF*32);
        float4* dst = (float4*)sA;
        #pragma unroll
        for (int i = 0; i < 6; ++i)
            dst[tid + i*512] = src[tid + i*512];
    }
    __syncthreads();
    const int w    = tid >> 6;                 // wave 0..7
    const int lane = tid & 63;
    const int bg   = w >> 1;                   // batch-group of 8 (wave-uniform)
    const int col4 = cblk*512 + (w & 1)*256 + lane*4;  // unique per lane

    float acc[8][4];
    #pragma unroll
    for (int i = 0; i < 8; ++i)
        #pragma unroll
        for (int j = 0; j < 4; ++j) acc[i][j] = 0.f;

    const float* tp    = Tm + (size_t)half*KHALF*NCOL + col4;
    const float* aBase = sA + bg*8;            // wave-uniform -> ds broadcast

#define TLD(KK) (*(const float4*)(tp + (size_t)(KK)*NCOL))
#define FM32(T4, AL, AH) { \
  acc[0][0]+=AL.x*T4.x; acc[0][1]+=AL.x*T4.y; acc[0][2]+=AL.x*T4.z; acc[0][3]+=AL.x*T4.w; \
  acc[1][0]+=AL.y*T4.x; acc[1][1]+=AL.y*T4.y; acc[1][2]+=AL.y*T4.z; acc[1][3]+=AL.y*T4.w; \
  acc[2][0]+=AL.z*T4.x; acc[2][1]+=AL.z*T4.y; acc[2][2]+=AL.z*T4.z; acc[2][3]+=AL.z*T4.w; \
  acc[3][0]+=AL.w*T4.x; acc[3][1]+=AL.w*T4.y; acc[3][2]+=AL.w*T4.z; acc[3][3]+=AL.w*T4.w; \
  acc[4][0]+=AH.x*T4.x; acc[4][1]+=AH.x*T4.y; acc[4][2]+=AH.x*T4.z; acc[4][3]+=AH.x*T4.w; \
  acc[5][0]+=AH.y*T4.x; acc[5][1]+=AH.y*T4.y; acc[5][2]+=AH.y*T4.z; acc[5][3]+=AH.y*T4.w; \
  acc[6][0]+=AH.z*T4.x; acc[6][1]+=AH.z*T4.y; acc[6][2]+=AH.z*T4.z; acc[6][3]+=AH.z*T4.w; \
  acc[7][0]+=AH.w*T4.x; acc[7][1]+=AH.w*T4.y; acc[7][2]+=AH.w*T4.z; acc[7][3]+=AH.w*T4.w; }
#define STEP(J, TT) { \
    const float4 aL = *(const float4*)(aBase + (k0+(J))*32); \
    const float4 aH = *(const float4*)(aBase + (k0+(J))*32 + 4); \
    FM32(TT, aL, aH); TT = TLD(k0 + 8 + (J)); }
#define STEPE(J, TT) { \
    const float4 aL = *(const float4*)(aBase + (k0+(J))*32); \
    const float4 aH = *(const float4*)(aBase + (k0+(J))*32 + 4); \
    FM32(TT, aL, aH); }

    float4 t0=TLD(0), t1=TLD(1), t2=TLD(2), t3=TLD(3),
           t4=TLD(4), t5=TLD(5), t6=TLD(6), t7=TLD(7);

    int k0 = 0;
    for (; k0 < KHALF - 8; k0 += 8) {
        STEP(0, t0) STEP(1, t1) STEP(2, t2) STEP(3, t3)
        STEP(4, t4) STEP(5, t5) STEP(6, t6) STEP(7, t7)
    }
    // epilogue: k0 == KHALF-8, consume only
    STEPE(0, t0) STEPE(1, t1) STEPE(2, t2) STEPE(3, t3)
    STEPE(4, t4) STEPE(5, t5) STEPE(6, t6) STEPE(7, t7)
#undef STEPE
#undef STEP
#undef FM32
#undef TLD

    #pragma unroll
    for (int bb = 0; bb < 8; ++bb)
        *(float4*)(Mp + ((size_t)half*NB + bg*8 + bb)*NCOL + col4) =
            make_float4(acc[bb][0], acc[bb][1], acc[bb][2], acc[bb][3]);
}

// K3: out[j,d] = sum_i exp(-sum_f |M[i,d,f]-M[j,d,f]|) - 1.
// Reads the two split-k partials and sums them during the LDS load.
__global__ __launch_bounds__(256) void k3_pairs(
    const float* __restrict__ Mp, float* __restrict__ outS)
{
    extern __shared__ float sM[];      // 32*32*17 floats
    const int tid = threadIdx.x;
    const int dd0 = blockIdx.x * 32;
    for (int idx = tid; idx < 32*32*16; idx += 256) {
        const int i = idx >> 9, rem = idx & 511, d = rem >> 4, f = rem & 15;
        const size_t off = (size_t)i*NCOL + (size_t)dd0*16 + rem;
        sM[(i*32 + d)*17 + f] = Mp[off] + Mp[off + (size_t)NB*NCOL];
    }
    __syncthreads();
    const int j = tid >> 3;
    for (int q = 0; q < 4; ++q) {
        const int d = (tid & 7) + q*8;
        float mj[16];
        const float* pj = sM + (j*32 + d)*17;
        #pragma unroll
        for (int f = 0; f < 16; ++f) mj[f] = pj[f];
        float acc = 0.f;
        for (int i = 0; i < 32; ++i) {
            const float* pi = sM + (i*32 + d)*17;
            float dist = 0.f;
            #pragma unroll
            for (int f = 0; f < 16; ++f) dist += fabsf(pi[f] - mj[f]);
            acc += __expf(-dist);
        }
        outS[(size_t)j*D_OUT + dd0 + d] = acc - 1.0f;
    }
}

// K4: ConvTranspose2d, stride==kernel -> no overlap.
__global__ __launch_bounds__(256) void k4_deconv(
    const float* __restrict__ outS, const float* __restrict__ wd,
    float* __restrict__ out)
{
    __shared__ float sO[32*256];       // [ic][si*16+sj]
    __shared__ float sWd[32*16];       // [ic][ki*4+kj]
    const int b   = blockIdx.x >> 5;
    const int oc  = blockIdx.x & 31;
    const int tid = threadIdx.x;
    for (int idx = tid; idx < 8192; idx += 256) sO[idx] = outS[(size_t)b*D_OUT + idx];
    for (int idx = tid; idx < 512; idx += 256) {
        const int ic = idx >> 4, r = idx & 15;
        sWd[idx] = wd[((ic*32 + oc) << 4) + r];   // IOHW: (ic, oc, ki, kj)
    }
    __syncthreads();
    float* ob = out + (size_t)b*BSTRIDE + (size_t)(128 + oc)*4096;
    for (int s = 0; s < 16; ++s) {
        const int p  = tid + (s << 8);
        const int i  = p >> 6, jc = p & 63;
        const int si = i >> 2, ki = i & 3, sj = jc >> 2, kj = jc & 3;
        float acc = 0.f;
        #pragma unroll
        for (int ic = 0; ic < 32; ++ic)
            acc += sO[ic*256 + si*16 + sj] * sWd[ic*16 + ki*4 + kj];
        ob[p] = acc;
    }
}

extern "C" void kernel_launch(void* const* d_in, const int* in_sizes, int n_in,
                              void* d_out, int out_size, void* d_ws, size_t ws_size,
                              hipStream_t stream) {
    const float* x  = (const float*)d_in[0];
    const float* wc = (const float*)d_in[1];
    const float* Tm = (const float*)d_in[2];
    const float* wd = (const float*)d_in[3];
    float* out  = (float*)d_out;
    float* At   = (float*)d_ws;                        // 96 KB @ 0
    float* Mp   = (float*)((char*)d_ws + (1 << 20));   // 33.6 MB @ 1 MB
    float* outS = (float*)((char*)d_ws + (1 << 20) + (1 << 26)); // 1 MB @ 68 MB

    k1_conv_copy<<<NB*TSP, 256, 0, stream>>>(x, wc, out, At);                   // 512 blocks
    k2_gemm    <<<512, 512, KHALF*32*sizeof(float), stream>>>(At, Tm, Mp);      // 2 halves x 256
    k3_pairs   <<<D_OUT/32, 256, 32*32*17*sizeof(float), stream>>>(Mp, outS);   // 256 blocks
    k4_deconv  <<<NB*OUTF, 256, 0, stream>>>(outS, wd, out);                    // 1024 blocks
}